// Round 13
// baseline (367.363 us; speedup 1.0000x reference)
//
#include <hip/hip_runtime.h>
#include <hip/hip_bf16.h>
#include <hip/hip_fp16.h>
#include <stdint.h>

#define Bc 4
#define Sc 2048
#define Ec 512
#define Hc 8
#define Dc 64
#define HDc 512

typedef __attribute__((ext_vector_type(8))) short bf16x8;
typedef __attribute__((ext_vector_type(2))) _Float16 f16x2;
typedef __attribute__((ext_vector_type(4))) _Float16 f16x4;
typedef __attribute__((ext_vector_type(8))) _Float16 f16x8;
typedef __attribute__((ext_vector_type(4))) float f32x4;
typedef __attribute__((ext_vector_type(16))) float f32x16;
typedef unsigned int u32;

__device__ __forceinline__ unsigned short f2bf(float x) {
    union { float f; unsigned u; } v; v.f = x;
    unsigned r = v.u + 0x7FFFu + ((v.u >> 16) & 1u);
    return (unsigned short)(r >> 16);
}

__device__ __forceinline__ unsigned pkbf2(float a, float b) {
    float2 f; f.x = a; f.y = b;
    __hip_bfloat162 h = __float22bfloat162_rn(f);
    union { __hip_bfloat162 h2; unsigned u; } u; u.h2 = h;
    return u.u;
}

__device__ __forceinline__ unsigned short f2h(float x) {
    return __half_as_ushort(__float2half_rn(x));
}

__device__ __forceinline__ unsigned pkh2(float a, float b) {
    union { __half2 h2; unsigned u; } u;
    u.h2 = __floats2half2_rn(a, b);
    return u.u;
}

__device__ __forceinline__ uint4 pack8(float4 a, float4 b) {
    uint4 v;
    v.x = pkbf2(a.x, a.y); v.y = pkbf2(a.z, a.w);
    v.z = pkbf2(b.x, b.y); v.w = pkbf2(b.z, b.w);
    return v;
}

// async global->LDS, 16B per lane; LDS dest = uniform base + lane*16
__device__ __forceinline__ void gload_lds(const void* g, void* l) {
    __builtin_amdgcn_global_load_lds(
        (const __attribute__((address_space(1))) u32*)g,
        (__attribute__((address_space(3))) u32*)l,
        16, 0, 0);
}

// ---------------------------------------------------------------------------
// Kernel 1: prep. blocks 0..255: weight transpose->bf16 Wt[z][n][k];
// 256..6399: X fp32 -> bf16 (q,k,v). Mask bit-pack moved into proj_gemm's
// grid (overlaps proj's compute blocks on the memory pipe).
__global__ __launch_bounds__(256) void prep(
    const float* __restrict__ W0, const float* __restrict__ W1,
    const float* __restrict__ W2, const float* __restrict__ W3,
    unsigned short* __restrict__ Wt,
    const float* __restrict__ Xq, const float* __restrict__ Xk,
    const float* __restrict__ Xv, unsigned short* __restrict__ Xb)
{
    const int blk = blockIdx.x;
    __shared__ float t[64][65];
    if (blk < 256) {
        const int z = blk >> 6;
        const float* W = z == 0 ? W0 : (z == 1 ? W1 : (z == 2 ? W2 : W3));
        unsigned short* O = Wt + (size_t)z * Ec * HDc;
        const int k0 = ((blk >> 3) & 7) * 64, n0 = (blk & 7) * 64;
#pragma unroll
        for (int i = 0; i < 16; i++) {
            int idx = threadIdx.x + 256 * i;
            int kr = idx >> 6, nc = idx & 63;
            t[nc][kr] = W[(size_t)(k0 + kr) * HDc + n0 + nc];
        }
        __syncthreads();
#pragma unroll
        for (int i = 0; i < 16; i++) {
            int idx = threadIdx.x + 256 * i;
            int nr = idx >> 6, kc = idx & 63;
            O[(size_t)(n0 + nr) * Ec + k0 + kc] = f2bf(t[nr][kc]);
        }
    } else {
        const int zi = blk - 256;
        const int z = zi >> 11, wi = zi & 2047;
        const float* X = z == 0 ? Xq : (z == 1 ? Xk : Xv);
        const size_t off = ((size_t)wi * 256 + threadIdx.x) * 8;
        const float4* p = (const float4*)(X + off);
        float4 f0 = p[0], f1 = p[1];
        *(uint4*)(Xb + (size_t)z * 4194304 + off) = pack8(f0, f1);
    }
}

// ---------------------------------------------------------------------------
// Kernel 2: fused QKV projection + mask bit-pack. 1D grid 1792 blocks:
// blk < 768 -> 128x128 GEMM tiles (z = blk>>8; rem: 64 m x 4 n), both
// operands via global_load_lds (bf16). blk >= 768 -> 1024 streaming blocks
// bit-packing the mask (overlaps the compute blocks on the memory pipe;
// all blocks co-resident at ~4 blocks/CU).
// z=0 -> Q (pre-scaled 1/8, exact pow2; attn uses fast __expf = mul+v_exp);
// z=1 -> K; z=2 -> V fp16, per-head transposed, NATURAL token order:
// Vt[b][h][d][tok] (32x32x16 f16 PV consumes tokens 8h+j contiguously).
__global__ __launch_bounds__(256) void proj_gemm(
    const unsigned short* __restrict__ Xb, const unsigned short* __restrict__ Wt,
    const float* __restrict__ bq, const float* __restrict__ bk, const float* __restrict__ bv,
    unsigned short* __restrict__ Oq, unsigned short* __restrict__ Ok,
    unsigned short* __restrict__ Vt,
    const int* __restrict__ mask, unsigned long long* __restrict__ bits)
{
    const int blk = blockIdx.x;
    if (blk >= 768) {
        // ---- mask bit-pack: 1024 blocks, 4096 waves, 64 words each ----
        const int lane = threadIdx.x & 63;
        int wave = ((blk - 768) * 256 + (int)threadIdx.x) >> 6;
        const int nwaves = (1024 * 256) >> 6;
        const int nwords = (Bc * Sc * Sc) / 64;
        for (int w = wave; w < nwords; w += nwaves) {
            int m = mask[(size_t)w * 64 + lane];
            unsigned long long b = __ballot(m != 0);
            if (lane == 0) bits[w] = b;
        }
        return;
    }
    const int z = blk >> 8;
    const int rem = blk & 255;
    const unsigned short* Xz = Xb + (size_t)z * 4194304;
    const unsigned short* Bt = Wt + (size_t)z * Ec * HDc;
    const float* bias = z == 0 ? bq : (z == 1 ? bk : bv);

    const int n0 = (rem & 3) * 128;
    const int m0 = (rem >> 2) * 128;
    const int tid = threadIdx.x, lane = tid & 63, w = tid >> 6;
    const int c = lane & 15, quad = lane >> 4;
    const int wm = w & 1, wn = w >> 1;

    __shared__ unsigned short As[128 * 64];
    __shared__ unsigned short Bs[128 * 64];

    f32x4 acc[4][4];
#pragma unroll
    for (int i = 0; i < 4; i++)
#pragma unroll
        for (int j = 0; j < 4; j++) acc[i][j] = (f32x4){0.f, 0.f, 0.f, 0.f};

    for (int k0 = 0; k0 < Ec; k0 += 64) {
        __syncthreads();
#pragma unroll
        for (int jj = 0; jj < 4; jj++) {
            int rb = w * 32 + jj * 8;
            int row = rb + (lane >> 3);
            int dg = (lane & 7) ^ (row & 7);
            gload_lds(Bt + (size_t)(n0 + row) * Ec + k0 + dg * 8, &Bs[rb * 64]);
            gload_lds(Xz + (size_t)(m0 + row) * Ec + k0 + dg * 8, &As[rb * 64]);
        }
        __syncthreads();
#pragma unroll
        for (int ks = 0; ks < 2; ks++) {
            int kg = ks * 4 + quad;
            bf16x8 af[4], bfr[4];
#pragma unroll
            for (int mt = 0; mt < 4; mt++) {
                int row = wm * 64 + mt * 16 + c;
                af[mt] = *(const bf16x8*)&As[row * 64 + ((kg ^ (row & 7)) * 8)];
            }
#pragma unroll
            for (int nt = 0; nt < 4; nt++) {
                int row = wn * 64 + nt * 16 + c;
                bfr[nt] = *(const bf16x8*)&Bs[row * 64 + ((kg ^ (row & 7)) * 8)];
            }
            if (z < 2) {
#pragma unroll
                for (int mt = 0; mt < 4; mt++)
#pragma unroll
                    for (int nt = 0; nt < 4; nt++)
                        acc[mt][nt] = __builtin_amdgcn_mfma_f32_16x16x32_bf16(af[mt], bfr[nt], acc[mt][nt], 0, 0, 0);
            } else {
#pragma unroll
                for (int mt = 0; mt < 4; mt++)
#pragma unroll
                    for (int nt = 0; nt < 4; nt++)
                        acc[mt][nt] = __builtin_amdgcn_mfma_f32_16x16x32_bf16(bfr[nt], af[mt], acc[mt][nt], 0, 0, 0);
            }
        }
    }

    if (z < 2) {
        unsigned short* O = z == 0 ? Oq : Ok;
        const float qs = z == 0 ? 0.125f : 1.0f;   // fold 1/sqrt(D) into Q (exact pow2)
#pragma unroll
        for (int mt = 0; mt < 4; mt++)
#pragma unroll
            for (int r = 0; r < 4; r++) {
                int gm = m0 + wm * 64 + mt * 16 + quad * 4 + r;
#pragma unroll
                for (int nt = 0; nt < 4; nt++) {
                    int gn = n0 + wn * 64 + nt * 16 + c;
                    O[(size_t)gm * HDc + gn] = f2bf((acc[mt][nt][r] + bias[gn]) * qs);
                }
            }
    } else {
        // transposed V epilogue, natural token order. acc cols = token (c), rows = d.
#pragma unroll
        for (int mt = 0; mt < 4; mt++) {
            int gm = m0 + wm * 64 + mt * 16 + c;     // token
            int bb = gm >> 11, sPos = gm & (Sc - 1);
#pragma unroll
            for (int nt = 0; nt < 4; nt++)
#pragma unroll
                for (int r = 0; r < 4; r++) {
                    int ng = n0 + wn * 64 + nt * 16 + quad * 4 + r;
                    int hh = ng >> 6, d = ng & 63;
                    Vt[((size_t)(bb * Hc + hh) * Dc + d) * Sc + sPos] = f2h(acc[mt][nt][r] + bias[ng]);
                }
        }
    }
}

// ---------------------------------------------------------------------------
// Kernel 3: flash attention — EXACT R11 kernel (measured 72.3-73.3 us best).
// S^T form, 32x32 MFMA grid, TOKEN-SPLIT x2. Block = 64 q x 4 waves:
// wave w -> token half (w>>1), q-group (w&1). Each half single-buffers its
// own 64-token K/V tiles (16 KB); LDS 32 KB -> 4 blocks/CU = 16 waves/CU.
// Partials over disjoint token halves merge EXACTLY by addition (no-max
// exp), LDS epilogue. XCD pin: flat&7 = head -> K/V L2-resident.
// EXP: __expf (fast path). Precise exp2f cost +12us (R9/R10); setprio
// neutral-negative here. stage loop MUST be jj<4 (R7/R8 NaN lesson).
__global__ __launch_bounds__(256, 4) void attn_kernel(
    const unsigned short* __restrict__ Qb, const unsigned short* __restrict__ Kb,
    const unsigned short* __restrict__ Vt, const unsigned long long* __restrict__ Mb,
    unsigned short* __restrict__ Ob)
{
    const int flat = blockIdx.x + 32 * blockIdx.y + 256 * blockIdx.z;
    const int hb = flat & 7;             // head -> XCD (dispatch round-robin)
    const int qt = (flat >> 3) & 31;     // 0..31, 64 q per block
    const int b  = flat >> 8;
    const int q0 = qt * 64;
    const int tid = threadIdx.x, lane = tid & 63, w = tid >> 6;
    const int l31 = lane & 31, hf = lane >> 5;
    const int half = w >> 1;             // token half: 0 -> tok 0..1023, 1 -> 1024..2047
    const int qgrp = w & 1;              // q-group within block

    // 32 KB shared: per-half single-buffered K and V tiles (64 tok x 64 d).
    // Reused as the f32 merge buffer at the epilogue.
    __shared__ unsigned short SM[16384];
    unsigned short* KsH = SM + half * 4096;
    unsigned short* VsH = SM + 8192 + half * 4096;

    const int qg = q0 + qgrp * 32 + l31;
    const size_t qoff = ((size_t)b * Sc + qg) * HDc + hb * Dc;

    // Q B-fragments: slice s4 holds d = 16*s4 + 8*hf + (0..7)
    bf16x8 qf[4];
#pragma unroll
    for (int s4 = 0; s4 < 4; s4++)
        qf[s4] = *(const bf16x8*)(Qb + qoff + s4 * 16 + hf * 8);

    const unsigned long long* mr = Mb + ((size_t)b * Sc + qg) * (Sc / 64);
    const size_t kbase = ((size_t)b * Sc) * HDc + hb * Dc;
    const size_t vbase = ((size_t)(b * Hc + hb)) * Dc * Sc;

    f32x16 o[2];
#pragma unroll
    for (int i = 0; i < 16; i++) { o[0][i] = 0.f; o[1][i] = 0.f; }
    float os[4] = {0.f, 0.f, 0.f, 0.f};
    const f16x2 one2 = {(_Float16)1.0f, (_Float16)1.0f};

    // stage tile t into this half's buffers; the half's 2 waves cooperate:
    // jj<4 x 8 rows x 2 waves = all 64 rows of K and V tiles.
    auto stage = [&](int t) {
#pragma unroll
        for (int jj = 0; jj < 4; jj++) {
            int rb = qgrp * 32 + jj * 8;
            int row = rb + (lane >> 3);
            int dg = (lane & 7) ^ (row & 7);
            gload_lds(Kb + kbase + (size_t)(t * 64 + row) * HDc + dg * 8, &KsH[rb * 64]);
            gload_lds(Vt + vbase + (size_t)row * Sc + t * 64 + dg * 8, &VsH[rb * 64]);
        }
    };

    for (int i = 0; i < 16; i++) {
        const int t = half * 16 + i;     // absolute 64-token tile id
        unsigned long long mw = mr[t];
        stage(t);
        __syncthreads();                 // drains async loads -> tiles ready

        // S^T per 32-token group: lane holds tok = 32a + 8g + 4hf + r, q = l31
        u32 P16[2][8];
#pragma unroll
        for (int a = 0; a < 2; a++) {
            f32x16 s;
#pragma unroll
            for (int i2 = 0; i2 < 16; i2++) s[i2] = 0.f;
            const int tk = a * 32 + l31;
#pragma unroll
            for (int s4 = 0; s4 < 4; s4++) {
                bf16x8 kf = *(const bf16x8*)&KsH[tk * 64 + (((2 * s4 + hf) ^ (tk & 7)) * 8)];
                s = __builtin_amdgcn_mfma_f32_32x32x16_bf16(kf, qf[s4], s, 0, 0, 0);
            }
            u32 mwa = (a == 0) ? (u32)mw : (u32)(mw >> 32);
            int mq = (int)(mwa >> (4 * hf));
#pragma unroll
            for (int g = 0; g < 4; g++) {
                float p[4];
#pragma unroll
                for (int r = 0; r < 4; r++) {
                    const int pos = 8 * g + r;                       // mask bit
                    int keep = __builtin_amdgcn_sbfe(mq, pos, 1);    // -1 if unmasked
                    float e = __expf(s[4 * g + r]);                  // fast path: mul + v_exp
                    p[r] = __int_as_float(__float_as_int(e) & keep);
                }
                u32 u0 = pkh2(p[0], p[1]);
                u32 u1 = pkh2(p[2], p[3]);
                P16[a][2 * g + 0] = u0;
                P16[a][2 * g + 1] = u1;
                union { u32 u; f16x2 h; } d0, d1;
                d0.u = u0; d1.u = u1;
                os[g] = __builtin_amdgcn_fdot2(d0.h, one2, os[g], false);
                os[g] = __builtin_amdgcn_fdot2(d1.h, one2, os[g], false);
            }
        }

        // Batched lane-half exchange (8 shfls issued together)
        u32 pw[4][4];
#pragma unroll
        for (int s4 = 0; s4 < 4; s4++) {
            const int a = s4 >> 1, base = 4 * (s4 & 1);
#pragma unroll
            for (int pp = 0; pp < 2; pp++) {
                u32 A0 = P16[a][base + pp];        // words for ho=0 tokens
                u32 B1 = P16[a][base + 2 + pp];    // words for ho=1 tokens
                u32 sent = hf ? A0 : B1;
                u32 got = (u32)__shfl_xor((int)sent, 32, 64);
                pw[s4][pp]     = hf ? got : A0;    // j=0..3  (from half 0)
                pw[s4][2 + pp] = hf ? B1  : got;   // j=4..7  (from half 1)
            }
        }
#pragma unroll
        for (int s4 = 0; s4 < 4; s4++) {
            union { u32 u[4]; f16x8 v; } pf;
            pf.u[0] = pw[s4][0]; pf.u[1] = pw[s4][1];
            pf.u[2] = pw[s4][2]; pf.u[3] = pw[s4][3];
#pragma unroll
            for (int dt = 0; dt < 2; dt++) {
                const int d = dt * 32 + l31;
                f16x8 vf = *(const f16x8*)&VsH[d * 64 + (((2 * s4 + hf) ^ (d & 7)) * 8)];
                o[dt] = __builtin_amdgcn_mfma_f32_32x32x16_f16(vf, pf.v, o[dt], 0, 0, 0);
            }
        }
        __syncthreads();                 // tiles reusable for next iteration
    }

    // each lane summed only its hf-half of its token range; partner lane
    // (lane^32) has the rest of this HALF's tokens
    float osum = os[0] + os[1] + os[2] + os[3];
    osum += __shfl_xor(osum, 32, 64);

    // ---- cross-half merge via LDS (exact: partials add, then normalize) ----
    float* mbuf = (float*)SM;            // [qgrp][lane][34] floats = 17.4 KB
    if (half == 1) {
        float* mp = mbuf + (qgrp * 64 + lane) * 34;
#pragma unroll
        for (int dt = 0; dt < 2; dt++)
#pragma unroll
            for (int i = 0; i < 16; i++) mp[dt * 16 + i] = o[dt][i];
        mp[32] = osum;
    }
    __syncthreads();
    if (half == 0) {
        const float* mp = mbuf + (qgrp * 64 + lane) * 34;
#pragma unroll
        for (int dt = 0; dt < 2; dt++)
#pragma unroll
            for (int i = 0; i < 16; i++) o[dt][i] += mp[dt * 16 + i];
        const float inv = 1.0f / (osum + mp[32]);
#pragma unroll
        for (int dt = 0; dt < 2; dt++)
#pragma unroll
            for (int g = 0; g < 4; g++) {
                const int d = dt * 32 + 8 * g + 4 * hf;
                uint2 pk;
                pk.x = pkbf2(o[dt][4 * g + 0] * inv, o[dt][4 * g + 1] * inv);
                pk.y = pkbf2(o[dt][4 * g + 2] * inv, o[dt][4 * g + 3] * inv);
                *(uint2*)(Ob + qoff + d) = pk;
            }
    }
}

// ---------------------------------------------------------------------------
// Kernel 4: output projection, 64x128 tiles. grid (4 n-blocks, 128 m-blocks).
__global__ __launch_bounds__(256) void out_gemm(
    const unsigned short* __restrict__ Ab, const unsigned short* __restrict__ Bt,
    const float* __restrict__ bias, float* __restrict__ Out)
{
    const int n0 = blockIdx.x * 128;
    const int m0 = blockIdx.y * 64;
    const int tid = threadIdx.x, lane = tid & 63, w = tid >> 6;
    const int c = lane & 15, quad = lane >> 4;
    const int wm = w & 1, wn = w >> 1;

    __shared__ unsigned short As[64 * 64];
    __shared__ unsigned short Bs[128 * 64];

    f32x4 acc[2][4];
#pragma unroll
    for (int i = 0; i < 2; i++)
#pragma unroll
        for (int j = 0; j < 4; j++) acc[i][j] = (f32x4){0.f, 0.f, 0.f, 0.f};

    for (int k0 = 0; k0 < HDc; k0 += 64) {
        __syncthreads();
#pragma unroll
        for (int jj = 0; jj < 4; jj++) {
            int rb = w * 32 + jj * 8;
            int row = rb + (lane >> 3);
            int dg = (lane & 7) ^ (row & 7);
            gload_lds(Bt + (size_t)(n0 + row) * Ec + k0 + dg * 8, &Bs[rb * 64]);
        }
#pragma unroll
        for (int jj = 0; jj < 2; jj++) {
            int rb = w * 16 + jj * 8;
            int row = rb + (lane >> 3);
            int dg = (lane & 7) ^ (row & 7);
            gload_lds(Ab + (size_t)(m0 + row) * HDc + k0 + dg * 8, &As[rb * 64]);
        }
        __syncthreads();
#pragma unroll
        for (int ks = 0; ks < 2; ks++) {
            int kg = ks * 4 + quad;
            bf16x8 af[2], bfr[4];
#pragma unroll
            for (int mt = 0; mt < 2; mt++) {
                int row = wm * 32 + mt * 16 + c;
                af[mt] = *(const bf16x8*)&As[row * 64 + ((kg ^ (row & 7)) * 8)];
            }
#pragma unroll
            for (int nt = 0; nt < 4; nt++) {
                int row = wn * 64 + nt * 16 + c;
                bfr[nt] = *(const bf16x8*)&Bs[row * 64 + ((kg ^ (row & 7)) * 8)];
            }
#pragma unroll
            for (int mt = 0; mt < 2; mt++)
#pragma unroll
                for (int nt = 0; nt < 4; nt++)
                    acc[mt][nt] = __builtin_amdgcn_mfma_f32_16x16x32_bf16(af[mt], bfr[nt], acc[mt][nt], 0, 0, 0);
        }
    }
#pragma unroll
    for (int mt = 0; mt < 2; mt++)
#pragma unroll
        for (int r = 0; r < 4; r++) {
            int gm = m0 + wm * 32 + mt * 16 + quad * 4 + r;
#pragma unroll
            for (int nt = 0; nt < 4; nt++) {
                int gn = n0 + wn * 64 + nt * 16 + c;
                Out[(size_t)gm * Ec + gn] = acc[mt][nt][r] + bias[gn];
            }
        }
}

// ---------------------------------------------------------------------------
extern "C" void kernel_launch(void* const* d_in, const int* in_sizes, int n_in,
                              void* d_out, int out_size, void* d_ws, size_t ws_size,
                              hipStream_t stream)
{
    const float* xq = (const float*)d_in[0];
    const float* xk = (const float*)d_in[1];
    const float* xv = (const float*)d_in[2];
    const int* mask = (const int*)d_in[3];
    const float* wq = (const float*)d_in[4];
    const float* bq = (const float*)d_in[5];
    const float* wk = (const float*)d_in[6];
    const float* bk = (const float*)d_in[7];
    const float* wv = (const float*)d_in[8];
    const float* bv = (const float*)d_in[9];
    const float* wo = (const float*)d_in[10];
    const float* bo = (const float*)d_in[11];
    float* out = (float*)d_out;

    char* ws = (char*)d_ws;
    const size_t MB = 1024 * 1024;
    unsigned short* qb = (unsigned short*)(ws + 0 * MB);    // 8 MB
    unsigned short* kb = (unsigned short*)(ws + 8 * MB);    // 8 MB
    unsigned short* vt = (unsigned short*)(ws + 16 * MB);   // 8 MB
    unsigned short* xb = (unsigned short*)(ws + 24 * MB);   // 24 MB (dead after proj)
    unsigned short* ab = (unsigned short*)(ws + 24 * MB);   // 8 MB (reuses xb space)
    unsigned long long* mb = (unsigned long long*)(ws + 48 * MB); // 2 MB
    unsigned short* wt = (unsigned short*)(ws + 50 * MB);   // 2 MB

    hipLaunchKernelGGL(prep, dim3(6400), dim3(256), 0, stream,
                       wq, wk, wv, wo, wt, xq, xk, xv, xb);

    hipLaunchKernelGGL(proj_gemm, dim3(1792), dim3(256), 0, stream,
                       xb, wt, bq, bk, bv, qb, kb, vt, mask, mb);

    hipLaunchKernelGGL(attn_kernel, dim3(32, 8, 4), dim3(256), 0, stream,
                       qb, kb, vt, mb, ab);

    hipLaunchKernelGGL(out_gemm, dim3(4, 128), dim3(256), 0, stream,
                       ab, wt + 3 * (size_t)Ec * HDc, bo, out);
}

// Round 14
// 269.068 us; speedup vs baseline: 1.3653x; 1.3653x over previous
//
#include <hip/hip_runtime.h>
#include <hip/hip_bf16.h>
#include <hip/hip_fp16.h>
#include <stdint.h>

#define Bc 4
#define Sc 2048
#define Ec 512
#define Hc 8
#define Dc 64
#define HDc 512

typedef __attribute__((ext_vector_type(8))) short bf16x8;
typedef __attribute__((ext_vector_type(2))) _Float16 f16x2;
typedef __attribute__((ext_vector_type(4))) _Float16 f16x4;
typedef __attribute__((ext_vector_type(8))) _Float16 f16x8;
typedef __attribute__((ext_vector_type(4))) float f32x4;
typedef __attribute__((ext_vector_type(16))) float f32x16;
typedef unsigned int u32;

__device__ __forceinline__ unsigned short f2bf(float x) {
    union { float f; unsigned u; } v; v.f = x;
    unsigned r = v.u + 0x7FFFu + ((v.u >> 16) & 1u);
    return (unsigned short)(r >> 16);
}

__device__ __forceinline__ unsigned pkbf2(float a, float b) {
    float2 f; f.x = a; f.y = b;
    __hip_bfloat162 h = __float22bfloat162_rn(f);
    union { __hip_bfloat162 h2; unsigned u; } u; u.h2 = h;
    return u.u;
}

__device__ __forceinline__ unsigned short f2h(float x) {
    return __half_as_ushort(__float2half_rn(x));
}

__device__ __forceinline__ unsigned pkh2(float a, float b) {
    union { __half2 h2; unsigned u; } u;
    u.h2 = __floats2half2_rn(a, b);
    return u.u;
}

__device__ __forceinline__ uint4 pack8(float4 a, float4 b) {
    uint4 v;
    v.x = pkbf2(a.x, a.y); v.y = pkbf2(a.z, a.w);
    v.z = pkbf2(b.x, b.y); v.w = pkbf2(b.z, b.w);
    return v;
}

// async global->LDS, 16B per lane; LDS dest = uniform base + lane*16
__device__ __forceinline__ void gload_lds(const void* g, void* l) {
    __builtin_amdgcn_global_load_lds(
        (const __attribute__((address_space(1))) u32*)g,
        (__attribute__((address_space(3))) u32*)l,
        16, 0, 0);
}

// ---------------------------------------------------------------------------
// Kernel 1: prep. blocks 0..255: weight transpose->bf16 Wt[z][n][k];
// 256..2303: mask bit-pack; 2304..8447: X fp32 -> bf16 (q,k,v).
// (R13 lesson: mask-pack must stay HERE — 8192 waves hidden under the
// X-convert stream; giving it dedicated long-running blocks in proj's grid
// serialized at 660 GB/s and cost +100 us.)
__global__ __launch_bounds__(256) void prep(
    const int* __restrict__ mask, unsigned long long* __restrict__ bits,
    const float* __restrict__ W0, const float* __restrict__ W1,
    const float* __restrict__ W2, const float* __restrict__ W3,
    unsigned short* __restrict__ Wt,
    const float* __restrict__ Xq, const float* __restrict__ Xk,
    const float* __restrict__ Xv, unsigned short* __restrict__ Xb)
{
    const int blk = blockIdx.x;
    __shared__ float t[64][65];
    if (blk < 256) {
        const int z = blk >> 6;
        const float* W = z == 0 ? W0 : (z == 1 ? W1 : (z == 2 ? W2 : W3));
        unsigned short* O = Wt + (size_t)z * Ec * HDc;
        const int k0 = ((blk >> 3) & 7) * 64, n0 = (blk & 7) * 64;
#pragma unroll
        for (int i = 0; i < 16; i++) {
            int idx = threadIdx.x + 256 * i;
            int kr = idx >> 6, nc = idx & 63;
            t[nc][kr] = W[(size_t)(k0 + kr) * HDc + n0 + nc];
        }
        __syncthreads();
#pragma unroll
        for (int i = 0; i < 16; i++) {
            int idx = threadIdx.x + 256 * i;
            int nr = idx >> 6, kc = idx & 63;
            O[(size_t)(n0 + nr) * Ec + k0 + kc] = f2bf(t[nr][kc]);
        }
    } else if (blk < 2304) {
        const int lane = threadIdx.x & 63;
        int wave = ((blk - 256) * 256 + (int)threadIdx.x) >> 6;
        const int nwaves = (2048 * 256) >> 6;
        const int nwords = (Bc * Sc * Sc) / 64;
        for (int w = wave; w < nwords; w += nwaves) {
            int m = mask[(size_t)w * 64 + lane];
            unsigned long long b = __ballot(m != 0);
            if (lane == 0) bits[w] = b;
        }
    } else {
        const int zi = blk - 2304;
        const int z = zi >> 11, wi = zi & 2047;
        const float* X = z == 0 ? Xq : (z == 1 ? Xk : Xv);
        const size_t off = ((size_t)wi * 256 + threadIdx.x) * 8;
        const float4* p = (const float4*)(X + off);
        float4 f0 = p[0], f1 = p[1];
        *(uint4*)(Xb + (size_t)z * 4194304 + off) = pack8(f0, f1);
    }
}

// ---------------------------------------------------------------------------
// Kernel 2: fused QKV projection, 128x128 tiles, both operands via
// global_load_lds (bf16). grid (4 n, 64 m, 3 z).
// z=0 -> Q (pre-scaled by 1/8 * log2(e): attn computes exp2(s) via the RAW
// v_exp_f32 builtin, no libm path); z=1 -> K; z=2 -> V fp16, per-head
// transposed, NATURAL token order: Vt[b][h][d][tok].
__global__ __launch_bounds__(256) void proj_gemm(
    const unsigned short* __restrict__ Xb, const unsigned short* __restrict__ Wt,
    const float* __restrict__ bq, const float* __restrict__ bk, const float* __restrict__ bv,
    unsigned short* __restrict__ Oq, unsigned short* __restrict__ Ok,
    unsigned short* __restrict__ Vt)
{
    const int z = blockIdx.z;
    const unsigned short* Xz = Xb + (size_t)z * 4194304;
    const unsigned short* Bt = Wt + (size_t)z * Ec * HDc;
    const float* bias = z == 0 ? bq : (z == 1 ? bk : bv);

    const int n0 = blockIdx.x * 128;
    const int m0 = blockIdx.y * 128;
    const int tid = threadIdx.x, lane = tid & 63, w = tid >> 6;
    const int c = lane & 15, quad = lane >> 4;
    const int wm = w & 1, wn = w >> 1;

    __shared__ unsigned short As[128 * 64];
    __shared__ unsigned short Bs[128 * 64];

    f32x4 acc[4][4];
#pragma unroll
    for (int i = 0; i < 4; i++)
#pragma unroll
        for (int j = 0; j < 4; j++) acc[i][j] = (f32x4){0.f, 0.f, 0.f, 0.f};

    for (int k0 = 0; k0 < Ec; k0 += 64) {
        __syncthreads();
#pragma unroll
        for (int jj = 0; jj < 4; jj++) {
            int rb = w * 32 + jj * 8;
            int row = rb + (lane >> 3);
            int dg = (lane & 7) ^ (row & 7);
            gload_lds(Bt + (size_t)(n0 + row) * Ec + k0 + dg * 8, &Bs[rb * 64]);
            gload_lds(Xz + (size_t)(m0 + row) * Ec + k0 + dg * 8, &As[rb * 64]);
        }
        __syncthreads();
#pragma unroll
        for (int ks = 0; ks < 2; ks++) {
            int kg = ks * 4 + quad;
            bf16x8 af[4], bfr[4];
#pragma unroll
            for (int mt = 0; mt < 4; mt++) {
                int row = wm * 64 + mt * 16 + c;
                af[mt] = *(const bf16x8*)&As[row * 64 + ((kg ^ (row & 7)) * 8)];
            }
#pragma unroll
            for (int nt = 0; nt < 4; nt++) {
                int row = wn * 64 + nt * 16 + c;
                bfr[nt] = *(const bf16x8*)&Bs[row * 64 + ((kg ^ (row & 7)) * 8)];
            }
            if (z < 2) {
#pragma unroll
                for (int mt = 0; mt < 4; mt++)
#pragma unroll
                    for (int nt = 0; nt < 4; nt++)
                        acc[mt][nt] = __builtin_amdgcn_mfma_f32_16x16x32_bf16(af[mt], bfr[nt], acc[mt][nt], 0, 0, 0);
            } else {
#pragma unroll
                for (int mt = 0; mt < 4; mt++)
#pragma unroll
                    for (int nt = 0; nt < 4; nt++)
                        acc[mt][nt] = __builtin_amdgcn_mfma_f32_16x16x32_bf16(bfr[nt], af[mt], acc[mt][nt], 0, 0, 0);
            }
        }
    }

    if (z < 2) {
        unsigned short* O = z == 0 ? Oq : Ok;
        // fold 1/sqrt(D) AND log2(e) into Q: attn computes exp2(s) = e^(qk/8)
        // (numerics proven in R5/R6: absmax 2.44e-4)
        const float qs = z == 0 ? 0.18033688011112043f : 1.0f;
#pragma unroll
        for (int mt = 0; mt < 4; mt++)
#pragma unroll
            for (int r = 0; r < 4; r++) {
                int gm = m0 + wm * 64 + mt * 16 + quad * 4 + r;
#pragma unroll
                for (int nt = 0; nt < 4; nt++) {
                    int gn = n0 + wn * 64 + nt * 16 + c;
                    O[(size_t)gm * HDc + gn] = f2bf((acc[mt][nt][r] + bias[gn]) * qs);
                }
            }
    } else {
        // transposed V epilogue, natural token order. acc cols = token (c), rows = d.
#pragma unroll
        for (int mt = 0; mt < 4; mt++) {
            int gm = m0 + wm * 64 + mt * 16 + c;     // token
            int bb = gm >> 11, sPos = gm & (Sc - 1);
#pragma unroll
            for (int nt = 0; nt < 4; nt++)
#pragma unroll
                for (int r = 0; r < 4; r++) {
                    int ng = n0 + wn * 64 + nt * 16 + quad * 4 + r;
                    int hh = ng >> 6, d = ng & 63;
                    Vt[((size_t)(bb * Hc + hh) * Dc + d) * Sc + sPos] = f2h(acc[mt][nt][r] + bias[ng]);
                }
        }
    }
}

// ---------------------------------------------------------------------------
// Kernel 3: flash attention — R11 structure (measured 72.3-73.3 us) + two
// evidence-backed deltas:
//  (a) raw-exp2 fold: Q pre-scaled by log2e/8, exp via
//      __builtin_amdgcn_exp2f = bare v_exp_f32 (no v_mul, no OCML slow
//      path — R10 showed precise exp2f costs ~8 VALU ops/exp = +12 us).
//  (b) setprio(1/0) around MFMA clusters (R9-vs-R10 A/B: -3.5 us;
//      catalog m191: attn +4-7%).
// S^T form, 32x32 MFMA grid, TOKEN-SPLIT x2; 64 q x 4 waves/block; per-half
// single-buffered 64-token K/V tiles; 4 blocks/CU. Exact merge by addition
// (no-max exp2). XCD pin: flat&7 = head. stage MUST be jj<4 (R7/R8 lesson).
__global__ __launch_bounds__(256, 4) void attn_kernel(
    const unsigned short* __restrict__ Qb, const unsigned short* __restrict__ Kb,
    const unsigned short* __restrict__ Vt, const unsigned long long* __restrict__ Mb,
    unsigned short* __restrict__ Ob)
{
    const int flat = blockIdx.x + 32 * blockIdx.y + 256 * blockIdx.z;
    const int hb = flat & 7;             // head -> XCD (dispatch round-robin)
    const int qt = (flat >> 3) & 31;     // 0..31, 64 q per block
    const int b  = flat >> 8;
    const int q0 = qt * 64;
    const int tid = threadIdx.x, lane = tid & 63, w = tid >> 6;
    const int l31 = lane & 31, hf = lane >> 5;
    const int half = w >> 1;             // token half: 0 -> tok 0..1023, 1 -> 1024..2047
    const int qgrp = w & 1;              // q-group within block

    // 32 KB shared: per-half single-buffered K and V tiles (64 tok x 64 d).
    // Reused as the f32 merge buffer at the epilogue.
    __shared__ unsigned short SM[16384];
    unsigned short* KsH = SM + half * 4096;
    unsigned short* VsH = SM + 8192 + half * 4096;

    const int qg = q0 + qgrp * 32 + l31;
    const size_t qoff = ((size_t)b * Sc + qg) * HDc + hb * Dc;

    // Q B-fragments: slice s4 holds d = 16*s4 + 8*hf + (0..7)
    bf16x8 qf[4];
#pragma unroll
    for (int s4 = 0; s4 < 4; s4++)
        qf[s4] = *(const bf16x8*)(Qb + qoff + s4 * 16 + hf * 8);

    const unsigned long long* mr = Mb + ((size_t)b * Sc + qg) * (Sc / 64);
    const size_t kbase = ((size_t)b * Sc) * HDc + hb * Dc;
    const size_t vbase = ((size_t)(b * Hc + hb)) * Dc * Sc;

    f32x16 o[2];
#pragma unroll
    for (int i = 0; i < 16; i++) { o[0][i] = 0.f; o[1][i] = 0.f; }
    float os[4] = {0.f, 0.f, 0.f, 0.f};
    const f16x2 one2 = {(_Float16)1.0f, (_Float16)1.0f};

    // stage tile t into this half's buffers; the half's 2 waves cooperate:
    // jj<4 x 8 rows x 2 waves = all 64 rows of K and V tiles.
    auto stage = [&](int t) {
#pragma unroll
        for (int jj = 0; jj < 4; jj++) {
            int rb = qgrp * 32 + jj * 8;
            int row = rb + (lane >> 3);
            int dg = (lane & 7) ^ (row & 7);
            gload_lds(Kb + kbase + (size_t)(t * 64 + row) * HDc + dg * 8, &KsH[rb * 64]);
            gload_lds(Vt + vbase + (size_t)row * Sc + t * 64 + dg * 8, &VsH[rb * 64]);
        }
    };

    for (int i = 0; i < 16; i++) {
        const int t = half * 16 + i;     // absolute 64-token tile id
        unsigned long long mw = mr[t];
        stage(t);
        __syncthreads();                 // drains async loads -> tiles ready

        // S^T per 32-token group: lane holds tok = 32a + 8g + 4hf + r, q = l31
        u32 P16[2][8];
#pragma unroll
        for (int a = 0; a < 2; a++) {
            f32x16 s;
#pragma unroll
            for (int i2 = 0; i2 < 16; i2++) s[i2] = 0.f;
            const int tk = a * 32 + l31;
            __builtin_amdgcn_s_setprio(1);
#pragma unroll
            for (int s4 = 0; s4 < 4; s4++) {
                bf16x8 kf = *(const bf16x8*)&KsH[tk * 64 + (((2 * s4 + hf) ^ (tk & 7)) * 8)];
                s = __builtin_amdgcn_mfma_f32_32x32x16_bf16(kf, qf[s4], s, 0, 0, 0);
            }
            __builtin_amdgcn_s_setprio(0);
            u32 mwa = (a == 0) ? (u32)mw : (u32)(mw >> 32);
            int mq = (int)(mwa >> (4 * hf));
#pragma unroll
            for (int g = 0; g < 4; g++) {
                float p[4];
#pragma unroll
                for (int r = 0; r < 4; r++) {
                    const int pos = 8 * g + r;                       // mask bit
                    int keep = __builtin_amdgcn_sbfe(mq, pos, 1);    // -1 if unmasked
                    float e = __builtin_amdgcn_exp2f(s[4 * g + r]);  // bare v_exp_f32
                    p[r] = __int_as_float(__float_as_int(e) & keep);
                }
                u32 u0 = pkh2(p[0], p[1]);
                u32 u1 = pkh2(p[2], p[3]);
                P16[a][2 * g + 0] = u0;
                P16[a][2 * g + 1] = u1;
                union { u32 u; f16x2 h; } d0, d1;
                d0.u = u0; d1.u = u1;
                os[g] = __builtin_amdgcn_fdot2(d0.h, one2, os[g], false);
                os[g] = __builtin_amdgcn_fdot2(d1.h, one2, os[g], false);
            }
        }

        // Batched lane-half exchange (8 shfls issued together)
        u32 pw[4][4];
#pragma unroll
        for (int s4 = 0; s4 < 4; s4++) {
            const int a = s4 >> 1, base = 4 * (s4 & 1);
#pragma unroll
            for (int pp = 0; pp < 2; pp++) {
                u32 A0 = P16[a][base + pp];        // words for ho=0 tokens
                u32 B1 = P16[a][base + 2 + pp];    // words for ho=1 tokens
                u32 sent = hf ? A0 : B1;
                u32 got = (u32)__shfl_xor((int)sent, 32, 64);
                pw[s4][pp]     = hf ? got : A0;    // j=0..3  (from half 0)
                pw[s4][2 + pp] = hf ? B1  : got;   // j=4..7  (from half 1)
            }
        }
        __builtin_amdgcn_s_setprio(1);
#pragma unroll
        for (int s4 = 0; s4 < 4; s4++) {
            union { u32 u[4]; f16x8 v; } pf;
            pf.u[0] = pw[s4][0]; pf.u[1] = pw[s4][1];
            pf.u[2] = pw[s4][2]; pf.u[3] = pw[s4][3];
#pragma unroll
            for (int dt = 0; dt < 2; dt++) {
                const int d = dt * 32 + l31;
                f16x8 vf = *(const f16x8*)&VsH[d * 64 + (((2 * s4 + hf) ^ (d & 7)) * 8)];
                o[dt] = __builtin_amdgcn_mfma_f32_32x32x16_f16(vf, pf.v, o[dt], 0, 0, 0);
            }
        }
        __builtin_amdgcn_s_setprio(0);
        __syncthreads();                 // tiles reusable for next iteration
    }

    // each lane summed only its hf-half of its token range; partner lane
    // (lane^32) has the rest of this HALF's tokens
    float osum = os[0] + os[1] + os[2] + os[3];
    osum += __shfl_xor(osum, 32, 64);

    // ---- cross-half merge via LDS (exact: partials add, then normalize) ----
    float* mbuf = (float*)SM;            // [qgrp][lane][34] floats = 17.4 KB
    if (half == 1) {
        float* mp = mbuf + (qgrp * 64 + lane) * 34;
#pragma unroll
        for (int dt = 0; dt < 2; dt++)
#pragma unroll
            for (int i = 0; i < 16; i++) mp[dt * 16 + i] = o[dt][i];
        mp[32] = osum;
    }
    __syncthreads();
    if (half == 0) {
        const float* mp = mbuf + (qgrp * 64 + lane) * 34;
#pragma unroll
        for (int dt = 0; dt < 2; dt++)
#pragma unroll
            for (int i = 0; i < 16; i++) o[dt][i] += mp[dt * 16 + i];
        const float inv = 1.0f / (osum + mp[32]);
#pragma unroll
        for (int dt = 0; dt < 2; dt++)
#pragma unroll
            for (int g = 0; g < 4; g++) {
                const int d = dt * 32 + 8 * g + 4 * hf;
                uint2 pk;
                pk.x = pkbf2(o[dt][4 * g + 0] * inv, o[dt][4 * g + 1] * inv);
                pk.y = pkbf2(o[dt][4 * g + 2] * inv, o[dt][4 * g + 3] * inv);
                *(uint2*)(Ob + qoff + d) = pk;
            }
    }
}

// ---------------------------------------------------------------------------
// Kernel 4: output projection, 64x128 tiles. grid (4 n-blocks, 128 m-blocks).
__global__ __launch_bounds__(256) void out_gemm(
    const unsigned short* __restrict__ Ab, const unsigned short* __restrict__ Bt,
    const float* __restrict__ bias, float* __restrict__ Out)
{
    const int n0 = blockIdx.x * 128;
    const int m0 = blockIdx.y * 64;
    const int tid = threadIdx.x, lane = tid & 63, w = tid >> 6;
    const int c = lane & 15, quad = lane >> 4;
    const int wm = w & 1, wn = w >> 1;

    __shared__ unsigned short As[64 * 64];
    __shared__ unsigned short Bs[128 * 64];

    f32x4 acc[2][4];
#pragma unroll
    for (int i = 0; i < 2; i++)
#pragma unroll
        for (int j = 0; j < 4; j++) acc[i][j] = (f32x4){0.f, 0.f, 0.f, 0.f};

    for (int k0 = 0; k0 < HDc; k0 += 64) {
        __syncthreads();
#pragma unroll
        for (int jj = 0; jj < 4; jj++) {
            int rb = w * 32 + jj * 8;
            int row = rb + (lane >> 3);
            int dg = (lane & 7) ^ (row & 7);
            gload_lds(Bt + (size_t)(n0 + row) * Ec + k0 + dg * 8, &Bs[rb * 64]);
        }
#pragma unroll
        for (int jj = 0; jj < 2; jj++) {
            int rb = w * 16 + jj * 8;
            int row = rb + (lane >> 3);
            int dg = (lane & 7) ^ (row & 7);
            gload_lds(Ab + (size_t)(m0 + row) * HDc + k0 + dg * 8, &As[rb * 64]);
        }
        __syncthreads();
#pragma unroll
        for (int ks = 0; ks < 2; ks++) {
            int kg = ks * 4 + quad;
            bf16x8 af[2], bfr[4];
#pragma unroll
            for (int mt = 0; mt < 2; mt++) {
                int row = wm * 32 + mt * 16 + c;
                af[mt] = *(const bf16x8*)&As[row * 64 + ((kg ^ (row & 7)) * 8)];
            }
#pragma unroll
            for (int nt = 0; nt < 4; nt++) {
                int row = wn * 64 + nt * 16 + c;
                bfr[nt] = *(const bf16x8*)&Bs[row * 64 + ((kg ^ (row & 7)) * 8)];
            }
#pragma unroll
            for (int mt = 0; mt < 2; mt++)
#pragma unroll
                for (int nt = 0; nt < 4; nt++)
                    acc[mt][nt] = __builtin_amdgcn_mfma_f32_16x16x32_bf16(af[mt], bfr[nt], acc[mt][nt], 0, 0, 0);
        }
    }
#pragma unroll
    for (int mt = 0; mt < 2; mt++)
#pragma unroll
        for (int r = 0; r < 4; r++) {
            int gm = m0 + wm * 32 + mt * 16 + quad * 4 + r;
#pragma unroll
            for (int nt = 0; nt < 4; nt++) {
                int gn = n0 + wn * 64 + nt * 16 + c;
                Out[(size_t)gm * Ec + gn] = acc[mt][nt][r] + bias[gn];
            }
        }
}

// ---------------------------------------------------------------------------
extern "C" void kernel_launch(void* const* d_in, const int* in_sizes, int n_in,
                              void* d_out, int out_size, void* d_ws, size_t ws_size,
                              hipStream_t stream)
{
    const float* xq = (const float*)d_in[0];
    const float* xk = (const float*)d_in[1];
    const float* xv = (const float*)d_in[2];
    const int* mask = (const int*)d_in[3];
    const float* wq = (const float*)d_in[4];
    const float* bq = (const float*)d_in[5];
    const float* wk = (const float*)d_in[6];
    const float* bk = (const float*)d_in[7];
    const float* wv = (const float*)d_in[8];
    const float* bv = (const float*)d_in[9];
    const float* wo = (const float*)d_in[10];
    const float* bo = (const float*)d_in[11];
    float* out = (float*)d_out;

    char* ws = (char*)d_ws;
    const size_t MB = 1024 * 1024;
    unsigned short* qb = (unsigned short*)(ws + 0 * MB);    // 8 MB
    unsigned short* kb = (unsigned short*)(ws + 8 * MB);    // 8 MB
    unsigned short* vt = (unsigned short*)(ws + 16 * MB);   // 8 MB
    unsigned short* xb = (unsigned short*)(ws + 24 * MB);   // 24 MB (dead after proj)
    unsigned short* ab = (unsigned short*)(ws + 24 * MB);   // 8 MB (reuses xb space)
    unsigned long long* mb = (unsigned long long*)(ws + 48 * MB); // 2 MB
    unsigned short* wt = (unsigned short*)(ws + 50 * MB);   // 2 MB

    hipLaunchKernelGGL(prep, dim3(8448), dim3(256), 0, stream,
                       mask, mb, wq, wk, wv, wo, wt, xq, xk, xv, xb);

    hipLaunchKernelGGL(proj_gemm, dim3(4, 64, 3), dim3(256), 0, stream,
                       xb, wt, bq, bk, bv, qb, kb, vt);

    hipLaunchKernelGGL(attn_kernel, dim3(32, 8, 4), dim3(256), 0, stream,
                       qb, kb, vt, mb, ab);

    hipLaunchKernelGGL(out_gemm, dim3(4, 128), dim3(256), 0, stream,
                       ab, wt + 3 * (size_t)Ec * HDc, bo, out);
}

// Round 15
// 265.077 us; speedup vs baseline: 1.3859x; 1.0151x over previous
//
#include <hip/hip_runtime.h>
#include <hip/hip_bf16.h>
#include <hip/hip_fp16.h>
#include <stdint.h>

#define Bc 4
#define Sc 2048
#define Ec 512
#define Hc 8
#define Dc 64
#define HDc 512

typedef __attribute__((ext_vector_type(8))) short bf16x8;
typedef __attribute__((ext_vector_type(2))) _Float16 f16x2;
typedef __attribute__((ext_vector_type(4))) _Float16 f16x4;
typedef __attribute__((ext_vector_type(8))) _Float16 f16x8;
typedef __attribute__((ext_vector_type(4))) float f32x4;
typedef __attribute__((ext_vector_type(16))) float f32x16;
typedef unsigned int u32;

__device__ __forceinline__ unsigned short f2bf(float x) {
    union { float f; unsigned u; } v; v.f = x;
    unsigned r = v.u + 0x7FFFu + ((v.u >> 16) & 1u);
    return (unsigned short)(r >> 16);
}

__device__ __forceinline__ unsigned pkbf2(float a, float b) {
    float2 f; f.x = a; f.y = b;
    __hip_bfloat162 h = __float22bfloat162_rn(f);
    union { __hip_bfloat162 h2; unsigned u; } u; u.h2 = h;
    return u.u;
}

__device__ __forceinline__ unsigned short f2h(float x) {
    return __half_as_ushort(__float2half_rn(x));
}

__device__ __forceinline__ unsigned pkh2(float a, float b) {
    union { __half2 h2; unsigned u; } u;
    u.h2 = __floats2half2_rn(a, b);
    return u.u;
}

__device__ __forceinline__ uint4 pack8(float4 a, float4 b) {
    uint4 v;
    v.x = pkbf2(a.x, a.y); v.y = pkbf2(a.z, a.w);
    v.z = pkbf2(b.x, b.y); v.w = pkbf2(b.z, b.w);
    return v;
}

// async global->LDS, 16B per lane; LDS dest = uniform base + lane*16
__device__ __forceinline__ void gload_lds(const void* g, void* l) {
    __builtin_amdgcn_global_load_lds(
        (const __attribute__((address_space(1))) u32*)g,
        (__attribute__((address_space(3))) u32*)l,
        16, 0, 0);
}

// ---------------------------------------------------------------------------
// Kernel 1: prep. blocks 0..255: weight transpose->bf16 Wt[z][n][k];
// 256..2303: mask bit-pack; 2304..8447: X fp32 -> bf16 (q,k,v).
// (R13 lesson: mask-pack must stay HERE — hidden under the X-convert
// stream; dedicated blocks in proj's grid serialized and cost +100 us.)
__global__ __launch_bounds__(256) void prep(
    const int* __restrict__ mask, unsigned long long* __restrict__ bits,
    const float* __restrict__ W0, const float* __restrict__ W1,
    const float* __restrict__ W2, const float* __restrict__ W3,
    unsigned short* __restrict__ Wt,
    const float* __restrict__ Xq, const float* __restrict__ Xk,
    const float* __restrict__ Xv, unsigned short* __restrict__ Xb)
{
    const int blk = blockIdx.x;
    __shared__ float t[64][65];
    if (blk < 256) {
        const int z = blk >> 6;
        const float* W = z == 0 ? W0 : (z == 1 ? W1 : (z == 2 ? W2 : W3));
        unsigned short* O = Wt + (size_t)z * Ec * HDc;
        const int k0 = ((blk >> 3) & 7) * 64, n0 = (blk & 7) * 64;
#pragma unroll
        for (int i = 0; i < 16; i++) {
            int idx = threadIdx.x + 256 * i;
            int kr = idx >> 6, nc = idx & 63;
            t[nc][kr] = W[(size_t)(k0 + kr) * HDc + n0 + nc];
        }
        __syncthreads();
#pragma unroll
        for (int i = 0; i < 16; i++) {
            int idx = threadIdx.x + 256 * i;
            int nr = idx >> 6, kc = idx & 63;
            O[(size_t)(n0 + nr) * Ec + k0 + kc] = f2bf(t[nr][kc]);
        }
    } else if (blk < 2304) {
        const int lane = threadIdx.x & 63;
        int wave = ((blk - 256) * 256 + (int)threadIdx.x) >> 6;
        const int nwaves = (2048 * 256) >> 6;
        const int nwords = (Bc * Sc * Sc) / 64;
        for (int w = wave; w < nwords; w += nwaves) {
            int m = mask[(size_t)w * 64 + lane];
            unsigned long long b = __ballot(m != 0);
            if (lane == 0) bits[w] = b;
        }
    } else {
        const int zi = blk - 2304;
        const int z = zi >> 11, wi = zi & 2047;
        const float* X = z == 0 ? Xq : (z == 1 ? Xk : Xv);
        const size_t off = ((size_t)wi * 256 + threadIdx.x) * 8;
        const float4* p = (const float4*)(X + off);
        float4 f0 = p[0], f1 = p[1];
        *(uint4*)(Xb + (size_t)z * 4194304 + off) = pack8(f0, f1);
    }
}

// ---------------------------------------------------------------------------
// Kernel 2: fused QKV projection, 128x128 tiles, both operands via
// global_load_lds (bf16). grid (4 n, 64 m, 3 z).
// z=0 -> Q (pre-scaled by 1/8 * log2(e): attn computes exp2(s) via the RAW
// v_exp_f32 builtin, no libm path); z=1 -> K; z=2 -> V fp16, per-head
// transposed, NATURAL token order: Vt[b][h][d][tok].
__global__ __launch_bounds__(256) void proj_gemm(
    const unsigned short* __restrict__ Xb, const unsigned short* __restrict__ Wt,
    const float* __restrict__ bq, const float* __restrict__ bk, const float* __restrict__ bv,
    unsigned short* __restrict__ Oq, unsigned short* __restrict__ Ok,
    unsigned short* __restrict__ Vt)
{
    const int z = blockIdx.z;
    const unsigned short* Xz = Xb + (size_t)z * 4194304;
    const unsigned short* Bt = Wt + (size_t)z * Ec * HDc;
    const float* bias = z == 0 ? bq : (z == 1 ? bk : bv);

    const int n0 = blockIdx.x * 128;
    const int m0 = blockIdx.y * 128;
    const int tid = threadIdx.x, lane = tid & 63, w = tid >> 6;
    const int c = lane & 15, quad = lane >> 4;
    const int wm = w & 1, wn = w >> 1;

    __shared__ unsigned short As[128 * 64];
    __shared__ unsigned short Bs[128 * 64];

    f32x4 acc[4][4];
#pragma unroll
    for (int i = 0; i < 4; i++)
#pragma unroll
        for (int j = 0; j < 4; j++) acc[i][j] = (f32x4){0.f, 0.f, 0.f, 0.f};

    for (int k0 = 0; k0 < Ec; k0 += 64) {
        __syncthreads();
#pragma unroll
        for (int jj = 0; jj < 4; jj++) {
            int rb = w * 32 + jj * 8;
            int row = rb + (lane >> 3);
            int dg = (lane & 7) ^ (row & 7);
            gload_lds(Bt + (size_t)(n0 + row) * Ec + k0 + dg * 8, &Bs[rb * 64]);
            gload_lds(Xz + (size_t)(m0 + row) * Ec + k0 + dg * 8, &As[rb * 64]);
        }
        __syncthreads();
#pragma unroll
        for (int ks = 0; ks < 2; ks++) {
            int kg = ks * 4 + quad;
            bf16x8 af[4], bfr[4];
#pragma unroll
            for (int mt = 0; mt < 4; mt++) {
                int row = wm * 64 + mt * 16 + c;
                af[mt] = *(const bf16x8*)&As[row * 64 + ((kg ^ (row & 7)) * 8)];
            }
#pragma unroll
            for (int nt = 0; nt < 4; nt++) {
                int row = wn * 64 + nt * 16 + c;
                bfr[nt] = *(const bf16x8*)&Bs[row * 64 + ((kg ^ (row & 7)) * 8)];
            }
            if (z < 2) {
#pragma unroll
                for (int mt = 0; mt < 4; mt++)
#pragma unroll
                    for (int nt = 0; nt < 4; nt++)
                        acc[mt][nt] = __builtin_amdgcn_mfma_f32_16x16x32_bf16(af[mt], bfr[nt], acc[mt][nt], 0, 0, 0);
            } else {
#pragma unroll
                for (int mt = 0; mt < 4; mt++)
#pragma unroll
                    for (int nt = 0; nt < 4; nt++)
                        acc[mt][nt] = __builtin_amdgcn_mfma_f32_16x16x32_bf16(bfr[nt], af[mt], acc[mt][nt], 0, 0, 0);
            }
        }
    }

    if (z < 2) {
        unsigned short* O = z == 0 ? Oq : Ok;
        // fold 1/sqrt(D) AND log2(e) into Q: attn computes exp2(s) = e^(qk/8)
        // (numerics proven R5/R6/R14: absmax 2.44e-4)
        const float qs = z == 0 ? 0.18033688011112043f : 1.0f;
#pragma unroll
        for (int mt = 0; mt < 4; mt++)
#pragma unroll
            for (int r = 0; r < 4; r++) {
                int gm = m0 + wm * 64 + mt * 16 + quad * 4 + r;
#pragma unroll
                for (int nt = 0; nt < 4; nt++) {
                    int gn = n0 + wn * 64 + nt * 16 + c;
                    O[(size_t)gm * HDc + gn] = f2bf((acc[mt][nt][r] + bias[gn]) * qs);
                }
            }
    } else {
        // transposed V epilogue, natural token order. acc cols = token (c), rows = d.
#pragma unroll
        for (int mt = 0; mt < 4; mt++) {
            int gm = m0 + wm * 64 + mt * 16 + c;     // token
            int bb = gm >> 11, sPos = gm & (Sc - 1);
#pragma unroll
            for (int nt = 0; nt < 4; nt++)
#pragma unroll
                for (int r = 0; r < 4; r++) {
                    int ng = n0 + wn * 64 + nt * 16 + quad * 4 + r;
                    int hh = ng >> 6, d = ng & 63;
                    Vt[((size_t)(bb * Hc + hh) * Dc + d) * Sc + sPos] = f2h(acc[mt][nt][r] + bias[ng]);
                }
        }
    }
}

// ---------------------------------------------------------------------------
// Kernel 3: flash attention — R14 kernel (measured 68.4-68.7 us) + row-sum
// moved from VALU to MFMA pipe: the 16 fdot2/tile are replaced by 4
// ones-MFMAs in the PV loop (A=ones -> every output row = rowsum; lane's
// col = q). Post-exchange pf.v spans BOTH lane-halves' tokens, so the sum
// is complete — the epilogue shfl_xor half-combine is deleted too.
// S^T form, 32x32 MFMA grid, TOKEN-SPLIT x2; 64 q x 4 waves/block; per-half
// single-buffered 64-token K/V tiles; 4 blocks/CU. Exact merge by addition
// (no-max exp2). XCD pin: flat&7 = head. stage MUST be jj<4 (R7/R8 lesson).
// exp: raw v_exp_f32 (R14: precise exp2f costs ~8 VALU ops/exp = +12 us).
__global__ __launch_bounds__(256, 4) void attn_kernel(
    const unsigned short* __restrict__ Qb, const unsigned short* __restrict__ Kb,
    const unsigned short* __restrict__ Vt, const unsigned long long* __restrict__ Mb,
    unsigned short* __restrict__ Ob)
{
    const int flat = blockIdx.x + 32 * blockIdx.y + 256 * blockIdx.z;
    const int hb = flat & 7;             // head -> XCD (dispatch round-robin)
    const int qt = (flat >> 3) & 31;     // 0..31, 64 q per block
    const int b  = flat >> 8;
    const int q0 = qt * 64;
    const int tid = threadIdx.x, lane = tid & 63, w = tid >> 6;
    const int l31 = lane & 31, hf = lane >> 5;
    const int half = w >> 1;             // token half: 0 -> tok 0..1023, 1 -> 1024..2047
    const int qgrp = w & 1;              // q-group within block

    // 32 KB shared: per-half single-buffered K and V tiles (64 tok x 64 d).
    // Reused as the f32 merge buffer at the epilogue.
    __shared__ unsigned short SM[16384];
    unsigned short* KsH = SM + half * 4096;
    unsigned short* VsH = SM + 8192 + half * 4096;

    const int qg = q0 + qgrp * 32 + l31;
    const size_t qoff = ((size_t)b * Sc + qg) * HDc + hb * Dc;

    // Q B-fragments: slice s4 holds d = 16*s4 + 8*hf + (0..7)
    bf16x8 qf[4];
#pragma unroll
    for (int s4 = 0; s4 < 4; s4++)
        qf[s4] = *(const bf16x8*)(Qb + qoff + s4 * 16 + hf * 8);

    const unsigned long long* mr = Mb + ((size_t)b * Sc + qg) * (Sc / 64);
    const size_t kbase = ((size_t)b * Sc) * HDc + hb * Dc;
    const size_t vbase = ((size_t)(b * Hc + hb)) * Dc * Sc;

    f32x16 o[2], osacc;
#pragma unroll
    for (int i = 0; i < 16; i++) { o[0][i] = 0.f; o[1][i] = 0.f; osacc[i] = 0.f; }
    const f16x8 ones8 = {(_Float16)1.0f, (_Float16)1.0f, (_Float16)1.0f, (_Float16)1.0f,
                         (_Float16)1.0f, (_Float16)1.0f, (_Float16)1.0f, (_Float16)1.0f};

    // stage tile t into this half's buffers; the half's 2 waves cooperate:
    // jj<4 x 8 rows x 2 waves = all 64 rows of K and V tiles.
    auto stage = [&](int t) {
#pragma unroll
        for (int jj = 0; jj < 4; jj++) {
            int rb = qgrp * 32 + jj * 8;
            int row = rb + (lane >> 3);
            int dg = (lane & 7) ^ (row & 7);
            gload_lds(Kb + kbase + (size_t)(t * 64 + row) * HDc + dg * 8, &KsH[rb * 64]);
            gload_lds(Vt + vbase + (size_t)row * Sc + t * 64 + dg * 8, &VsH[rb * 64]);
        }
    };

    for (int i = 0; i < 16; i++) {
        const int t = half * 16 + i;     // absolute 64-token tile id
        unsigned long long mw = mr[t];
        stage(t);
        __syncthreads();                 // drains async loads -> tiles ready

        // S^T per 32-token group: lane holds tok = 32a + 8g + 4hf + r, q = l31
        u32 P16[2][8];
#pragma unroll
        for (int a = 0; a < 2; a++) {
            f32x16 s;
#pragma unroll
            for (int i2 = 0; i2 < 16; i2++) s[i2] = 0.f;
            const int tk = a * 32 + l31;
            __builtin_amdgcn_s_setprio(1);
#pragma unroll
            for (int s4 = 0; s4 < 4; s4++) {
                bf16x8 kf = *(const bf16x8*)&KsH[tk * 64 + (((2 * s4 + hf) ^ (tk & 7)) * 8)];
                s = __builtin_amdgcn_mfma_f32_32x32x16_bf16(kf, qf[s4], s, 0, 0, 0);
            }
            __builtin_amdgcn_s_setprio(0);
            u32 mwa = (a == 0) ? (u32)mw : (u32)(mw >> 32);
            int mq = (int)(mwa >> (4 * hf));
#pragma unroll
            for (int g = 0; g < 4; g++) {
                float p[4];
#pragma unroll
                for (int r = 0; r < 4; r++) {
                    const int pos = 8 * g + r;                       // mask bit
                    int keep = __builtin_amdgcn_sbfe(mq, pos, 1);    // -1 if unmasked
                    float e = __builtin_amdgcn_exp2f(s[4 * g + r]);  // bare v_exp_f32
                    p[r] = __int_as_float(__float_as_int(e) & keep);
                }
                P16[a][2 * g + 0] = pkh2(p[0], p[1]);
                P16[a][2 * g + 1] = pkh2(p[2], p[3]);
            }
        }

        // Batched lane-half exchange (8 shfls issued together)
        u32 pw[4][4];
#pragma unroll
        for (int s4 = 0; s4 < 4; s4++) {
            const int a = s4 >> 1, base = 4 * (s4 & 1);
#pragma unroll
            for (int pp = 0; pp < 2; pp++) {
                u32 A0 = P16[a][base + pp];        // words for ho=0 tokens
                u32 B1 = P16[a][base + 2 + pp];    // words for ho=1 tokens
                u32 sent = hf ? A0 : B1;
                u32 got = (u32)__shfl_xor((int)sent, 32, 64);
                pw[s4][pp]     = hf ? got : A0;    // j=0..3  (from half 0)
                pw[s4][2 + pp] = hf ? B1  : got;   // j=4..7  (from half 1)
            }
        }
        __builtin_amdgcn_s_setprio(1);
#pragma unroll
        for (int s4 = 0; s4 < 4; s4++) {
            union { u32 u[4]; f16x8 v; } pf;
            pf.u[0] = pw[s4][0]; pf.u[1] = pw[s4][1];
            pf.u[2] = pw[s4][2]; pf.u[3] = pw[s4][3];
#pragma unroll
            for (int dt = 0; dt < 2; dt++) {
                const int d = dt * 32 + l31;
                f16x8 vf = *(const f16x8*)&VsH[d * 64 + (((2 * s4 + hf) ^ (d & 7)) * 8)];
                o[dt] = __builtin_amdgcn_mfma_f32_32x32x16_f16(vf, pf.v, o[dt], 0, 0, 0);
            }
            // row-sum on the MFMA pipe: A=ones -> every row of the result is
            // sum_k P[k][q]; pf.v spans both lane-halves' tokens of slice s4.
            osacc = __builtin_amdgcn_mfma_f32_32x32x16_f16(ones8, pf.v, osacc, 0, 0, 0);
        }
        __builtin_amdgcn_s_setprio(0);
        __syncthreads();                 // tiles reusable for next iteration
    }

    // osacc row 0 (any row) = full row-sum over this wave's token range.
    float osum = osacc[0];

    // ---- cross-half merge via LDS (exact: partials add, then normalize) ----
    float* mbuf = (float*)SM;            // [qgrp][lane][34] floats = 17.4 KB
    if (half == 1) {
        float* mp = mbuf + (qgrp * 64 + lane) * 34;
#pragma unroll
        for (int dt = 0; dt < 2; dt++)
#pragma unroll
            for (int i = 0; i < 16; i++) mp[dt * 16 + i] = o[dt][i];
        mp[32] = osum;
    }
    __syncthreads();
    if (half == 0) {
        const float* mp = mbuf + (qgrp * 64 + lane) * 34;
#pragma unroll
        for (int dt = 0; dt < 2; dt++)
#pragma unroll
            for (int i = 0; i < 16; i++) o[dt][i] += mp[dt * 16 + i];
        const float inv = 1.0f / (osum + mp[32]);
#pragma unroll
        for (int dt = 0; dt < 2; dt++)
#pragma unroll
            for (int g = 0; g < 4; g++) {
                const int d = dt * 32 + 8 * g + 4 * hf;
                uint2 pk;
                pk.x = pkbf2(o[dt][4 * g + 0] * inv, o[dt][4 * g + 1] * inv);
                pk.y = pkbf2(o[dt][4 * g + 2] * inv, o[dt][4 * g + 3] * inv);
                *(uint2*)(Ob + qoff + d) = pk;
            }
    }
}

// ---------------------------------------------------------------------------
// Kernel 4: output projection, 64x128 tiles. grid (4 n-blocks, 128 m-blocks).
__global__ __launch_bounds__(256) void out_gemm(
    const unsigned short* __restrict__ Ab, const unsigned short* __restrict__ Bt,
    const float* __restrict__ bias, float* __restrict__ Out)
{
    const int n0 = blockIdx.x * 128;
    const int m0 = blockIdx.y * 64;
    const int tid = threadIdx.x, lane = tid & 63, w = tid >> 6;
    const int c = lane & 15, quad = lane >> 4;
    const int wm = w & 1, wn = w >> 1;

    __shared__ unsigned short As[64 * 64];
    __shared__ unsigned short Bs[128 * 64];

    f32x4 acc[2][4];
#pragma unroll
    for (int i = 0; i < 2; i++)
#pragma unroll
        for (int j = 0; j < 4; j++) acc[i][j] = (f32x4){0.f, 0.f, 0.f, 0.f};

    for (int k0 = 0; k0 < HDc; k0 += 64) {
        __syncthreads();
#pragma unroll
        for (int jj = 0; jj < 4; jj++) {
            int rb = w * 32 + jj * 8;
            int row = rb + (lane >> 3);
            int dg = (lane & 7) ^ (row & 7);
            gload_lds(Bt + (size_t)(n0 + row) * Ec + k0 + dg * 8, &Bs[rb * 64]);
        }
#pragma unroll
        for (int jj = 0; jj < 2; jj++) {
            int rb = w * 16 + jj * 8;
            int row = rb + (lane >> 3);
            int dg = (lane & 7) ^ (row & 7);
            gload_lds(Ab + (size_t)(m0 + row) * HDc + k0 + dg * 8, &As[rb * 64]);
        }
        __syncthreads();
#pragma unroll
        for (int ks = 0; ks < 2; ks++) {
            int kg = ks * 4 + quad;
            bf16x8 af[2], bfr[4];
#pragma unroll
            for (int mt = 0; mt < 2; mt++) {
                int row = wm * 32 + mt * 16 + c;
                af[mt] = *(const bf16x8*)&As[row * 64 + ((kg ^ (row & 7)) * 8)];
            }
#pragma unroll
            for (int nt = 0; nt < 4; nt++) {
                int row = wn * 64 + nt * 16 + c;
                bfr[nt] = *(const bf16x8*)&Bs[row * 64 + ((kg ^ (row & 7)) * 8)];
            }
#pragma unroll
            for (int mt = 0; mt < 2; mt++)
#pragma unroll
                for (int nt = 0; nt < 4; nt++)
                    acc[mt][nt] = __builtin_amdgcn_mfma_f32_16x16x32_bf16(af[mt], bfr[nt], acc[mt][nt], 0, 0, 0);
        }
    }
#pragma unroll
    for (int mt = 0; mt < 2; mt++)
#pragma unroll
        for (int r = 0; r < 4; r++) {
            int gm = m0 + wm * 32 + mt * 16 + quad * 4 + r;
#pragma unroll
            for (int nt = 0; nt < 4; nt++) {
                int gn = n0 + wn * 64 + nt * 16 + c;
                Out[(size_t)gm * Ec + gn] = acc[mt][nt][r] + bias[gn];
            }
        }
}

// ---------------------------------------------------------------------------
extern "C" void kernel_launch(void* const* d_in, const int* in_sizes, int n_in,
                              void* d_out, int out_size, void* d_ws, size_t ws_size,
                              hipStream_t stream)
{
    const float* xq = (const float*)d_in[0];
    const float* xk = (const float*)d_in[1];
    const float* xv = (const float*)d_in[2];
    const int* mask = (const int*)d_in[3];
    const float* wq = (const float*)d_in[4];
    const float* bq = (const float*)d_in[5];
    const float* wk = (const float*)d_in[6];
    const float* bk = (const float*)d_in[7];
    const float* wv = (const float*)d_in[8];
    const float* bv = (const float*)d_in[9];
    const float* wo = (const float*)d_in[10];
    const float* bo = (const float*)d_in[11];
    float* out = (float*)d_out;

    char* ws = (char*)d_ws;
    const size_t MB = 1024 * 1024;
    unsigned short* qb = (unsigned short*)(ws + 0 * MB);    // 8 MB
    unsigned short* kb = (unsigned short*)(ws + 8 * MB);    // 8 MB
    unsigned short* vt = (unsigned short*)(ws + 16 * MB);   // 8 MB
    unsigned short* xb = (unsigned short*)(ws + 24 * MB);   // 24 MB (dead after proj)
    unsigned short* ab = (unsigned short*)(ws + 24 * MB);   // 8 MB (reuses xb space)
    unsigned long long* mb = (unsigned long long*)(ws + 48 * MB); // 2 MB
    unsigned short* wt = (unsigned short*)(ws + 50 * MB);   // 2 MB

    hipLaunchKernelGGL(prep, dim3(8448), dim3(256), 0, stream,
                       mask, mb, wq, wk, wv, wo, wt, xq, xk, xv, xb);

    hipLaunchKernelGGL(proj_gemm, dim3(4, 64, 3), dim3(256), 0, stream,
                       xb, wt, bq, bk, bv, qb, kb, vt);

    hipLaunchKernelGGL(attn_kernel, dim3(32, 8, 4), dim3(256), 0, stream,
                       qb, kb, vt, mb, ab);

    hipLaunchKernelGGL(out_gemm, dim3(4, 128), dim3(256), 0, stream,
                       ab, wt + 3 * (size_t)Ec * HDc, bo, out);
}

// Round 16
// 262.305 us; speedup vs baseline: 1.4005x; 1.0106x over previous
//
#include <hip/hip_runtime.h>
#include <hip/hip_bf16.h>
#include <hip/hip_fp16.h>
#include <stdint.h>

#define Bc 4
#define Sc 2048
#define Ec 512
#define Hc 8
#define Dc 64
#define HDc 512

typedef __attribute__((ext_vector_type(8))) short bf16x8;
typedef __attribute__((ext_vector_type(2))) _Float16 f16x2;
typedef __attribute__((ext_vector_type(4))) _Float16 f16x4;
typedef __attribute__((ext_vector_type(8))) _Float16 f16x8;
typedef __attribute__((ext_vector_type(4))) float f32x4;
typedef __attribute__((ext_vector_type(16))) float f32x16;
typedef unsigned int u32;

__device__ __forceinline__ unsigned short f2bf(float x) {
    union { float f; unsigned u; } v; v.f = x;
    unsigned r = v.u + 0x7FFFu + ((v.u >> 16) & 1u);
    return (unsigned short)(r >> 16);
}

__device__ __forceinline__ unsigned pkbf2(float a, float b) {
    float2 f; f.x = a; f.y = b;
    __hip_bfloat162 h = __float22bfloat162_rn(f);
    union { __hip_bfloat162 h2; unsigned u; } u; u.h2 = h;
    return u.u;
}

__device__ __forceinline__ unsigned short f2h(float x) {
    return __half_as_ushort(__float2half_rn(x));
}

__device__ __forceinline__ unsigned pkh2(float a, float b) {
    union { __half2 h2; unsigned u; } u;
    u.h2 = __floats2half2_rn(a, b);
    return u.u;
}

__device__ __forceinline__ uint4 pack8(float4 a, float4 b) {
    uint4 v;
    v.x = pkbf2(a.x, a.y); v.y = pkbf2(a.z, a.w);
    v.z = pkbf2(b.x, b.y); v.w = pkbf2(b.z, b.w);
    return v;
}

// async global->LDS, 16B per lane; LDS dest = uniform base + lane*16
__device__ __forceinline__ void gload_lds(const void* g, void* l) {
    __builtin_amdgcn_global_load_lds(
        (const __attribute__((address_space(1))) u32*)g,
        (__attribute__((address_space(3))) u32*)l,
        16, 0, 0);
}

// ---------------------------------------------------------------------------
// Kernel 1: prep. blocks 0..255: weight transpose->bf16 Wt[z][n][k];
// 256..2303: mask bit-pack; 2304..8447: X fp32 -> bf16 (q,k,v).
// (R13 lesson: mask-pack must stay HERE — hidden under the X-convert
// stream; dedicated blocks in proj's grid serialized and cost +100 us.)
__global__ __launch_bounds__(256) void prep(
    const int* __restrict__ mask, unsigned long long* __restrict__ bits,
    const float* __restrict__ W0, const float* __restrict__ W1,
    const float* __restrict__ W2, const float* __restrict__ W3,
    unsigned short* __restrict__ Wt,
    const float* __restrict__ Xq, const float* __restrict__ Xk,
    const float* __restrict__ Xv, unsigned short* __restrict__ Xb)
{
    const int blk = blockIdx.x;
    __shared__ float t[64][65];
    if (blk < 256) {
        const int z = blk >> 6;
        const float* W = z == 0 ? W0 : (z == 1 ? W1 : (z == 2 ? W2 : W3));
        unsigned short* O = Wt + (size_t)z * Ec * HDc;
        const int k0 = ((blk >> 3) & 7) * 64, n0 = (blk & 7) * 64;
#pragma unroll
        for (int i = 0; i < 16; i++) {
            int idx = threadIdx.x + 256 * i;
            int kr = idx >> 6, nc = idx & 63;
            t[nc][kr] = W[(size_t)(k0 + kr) * HDc + n0 + nc];
        }
        __syncthreads();
#pragma unroll
        for (int i = 0; i < 16; i++) {
            int idx = threadIdx.x + 256 * i;
            int nr = idx >> 6, kc = idx & 63;
            O[(size_t)(n0 + nr) * Ec + k0 + kc] = f2bf(t[nr][kc]);
        }
    } else if (blk < 2304) {
        const int lane = threadIdx.x & 63;
        int wave = ((blk - 256) * 256 + (int)threadIdx.x) >> 6;
        const int nwaves = (2048 * 256) >> 6;
        const int nwords = (Bc * Sc * Sc) / 64;
        for (int w = wave; w < nwords; w += nwaves) {
            int m = mask[(size_t)w * 64 + lane];
            unsigned long long b = __ballot(m != 0);
            if (lane == 0) bits[w] = b;
        }
    } else {
        const int zi = blk - 2304;
        const int z = zi >> 11, wi = zi & 2047;
        const float* X = z == 0 ? Xq : (z == 1 ? Xk : Xv);
        const size_t off = ((size_t)wi * 256 + threadIdx.x) * 8;
        const float4* p = (const float4*)(X + off);
        float4 f0 = p[0], f1 = p[1];
        *(uint4*)(Xb + (size_t)z * 4194304 + off) = pack8(f0, f1);
    }
}

// ---------------------------------------------------------------------------
// Kernel 2: fused QKV projection, 128x128 tiles, both operands via
// global_load_lds (bf16). grid (4 n, 64 m, 3 z).
// z=0 -> Q (pre-scaled by 1/8 * log2(e): attn computes exp2(s) via the RAW
// v_exp_f32 builtin, no libm path); z=1 -> K; z=2 -> V fp16, per-head
// transposed, NATURAL token order: Vt[b][h][d][tok].
__global__ __launch_bounds__(256) void proj_gemm(
    const unsigned short* __restrict__ Xb, const unsigned short* __restrict__ Wt,
    const float* __restrict__ bq, const float* __restrict__ bk, const float* __restrict__ bv,
    unsigned short* __restrict__ Oq, unsigned short* __restrict__ Ok,
    unsigned short* __restrict__ Vt)
{
    const int z = blockIdx.z;
    const unsigned short* Xz = Xb + (size_t)z * 4194304;
    const unsigned short* Bt = Wt + (size_t)z * Ec * HDc;
    const float* bias = z == 0 ? bq : (z == 1 ? bk : bv);

    const int n0 = blockIdx.x * 128;
    const int m0 = blockIdx.y * 128;
    const int tid = threadIdx.x, lane = tid & 63, w = tid >> 6;
    const int c = lane & 15, quad = lane >> 4;
    const int wm = w & 1, wn = w >> 1;

    __shared__ unsigned short As[128 * 64];
    __shared__ unsigned short Bs[128 * 64];

    f32x4 acc[4][4];
#pragma unroll
    for (int i = 0; i < 4; i++)
#pragma unroll
        for (int j = 0; j < 4; j++) acc[i][j] = (f32x4){0.f, 0.f, 0.f, 0.f};

    for (int k0 = 0; k0 < Ec; k0 += 64) {
        __syncthreads();
#pragma unroll
        for (int jj = 0; jj < 4; jj++) {
            int rb = w * 32 + jj * 8;
            int row = rb + (lane >> 3);
            int dg = (lane & 7) ^ (row & 7);
            gload_lds(Bt + (size_t)(n0 + row) * Ec + k0 + dg * 8, &Bs[rb * 64]);
            gload_lds(Xz + (size_t)(m0 + row) * Ec + k0 + dg * 8, &As[rb * 64]);
        }
        __syncthreads();
#pragma unroll
        for (int ks = 0; ks < 2; ks++) {
            int kg = ks * 4 + quad;
            bf16x8 af[4], bfr[4];
#pragma unroll
            for (int mt = 0; mt < 4; mt++) {
                int row = wm * 64 + mt * 16 + c;
                af[mt] = *(const bf16x8*)&As[row * 64 + ((kg ^ (row & 7)) * 8)];
            }
#pragma unroll
            for (int nt = 0; nt < 4; nt++) {
                int row = wn * 64 + nt * 16 + c;
                bfr[nt] = *(const bf16x8*)&Bs[row * 64 + ((kg ^ (row & 7)) * 8)];
            }
            if (z < 2) {
#pragma unroll
                for (int mt = 0; mt < 4; mt++)
#pragma unroll
                    for (int nt = 0; nt < 4; nt++)
                        acc[mt][nt] = __builtin_amdgcn_mfma_f32_16x16x32_bf16(af[mt], bfr[nt], acc[mt][nt], 0, 0, 0);
            } else {
#pragma unroll
                for (int mt = 0; mt < 4; mt++)
#pragma unroll
                    for (int nt = 0; nt < 4; nt++)
                        acc[mt][nt] = __builtin_amdgcn_mfma_f32_16x16x32_bf16(bfr[nt], af[mt], acc[mt][nt], 0, 0, 0);
            }
        }
    }

    if (z < 2) {
        unsigned short* O = z == 0 ? Oq : Ok;
        // fold 1/sqrt(D) AND log2(e) into Q: attn computes exp2(s) = e^(qk/8)
        // (numerics proven R5/R6/R14: absmax 2.44e-4)
        const float qs = z == 0 ? 0.18033688011112043f : 1.0f;
#pragma unroll
        for (int mt = 0; mt < 4; mt++)
#pragma unroll
            for (int r = 0; r < 4; r++) {
                int gm = m0 + wm * 64 + mt * 16 + quad * 4 + r;
#pragma unroll
                for (int nt = 0; nt < 4; nt++) {
                    int gn = n0 + wn * 64 + nt * 16 + c;
                    O[(size_t)gm * HDc + gn] = f2bf((acc[mt][nt][r] + bias[gn]) * qs);
                }
            }
    } else {
        // transposed V epilogue, natural token order. acc cols = token (c), rows = d.
#pragma unroll
        for (int mt = 0; mt < 4; mt++) {
            int gm = m0 + wm * 64 + mt * 16 + c;     // token
            int bb = gm >> 11, sPos = gm & (Sc - 1);
#pragma unroll
            for (int nt = 0; nt < 4; nt++)
#pragma unroll
                for (int r = 0; r < 4; r++) {
                    int ng = n0 + wn * 64 + nt * 16 + quad * 4 + r;
                    int hh = ng >> 6, d = ng & 63;
                    Vt[((size_t)(bb * Hc + hh) * Dc + d) * Sc + sPos] = f2h(acc[mt][nt][r] + bias[ng]);
                }
        }
    }
}

// ---------------------------------------------------------------------------
// Kernel 3: flash attention — R14 kernel (best measured: 68.4-68.7 us).
// S^T form, 32x32 MFMA grid, TOKEN-SPLIT x2; 64 q x 4 waves/block; per-half
// single-buffered 64-token K/V tiles; 4 blocks/CU. Exact merge by addition
// (no-max exp2). XCD pin: flat&7 = head -> K/V L2-resident.
//  - raw-exp2 fold: Q pre-scaled by log2e/8, exp = bare v_exp_f32
//    (R10: precise exp2f costs ~8 VALU ops/exp = +12 us).
//  - setprio(1/0) around MFMA clusters (R9-vs-R10 A/B: -3.5 us).
//  - row-sum via fdot2 on VALU (R15 ones-MFMA variant SPILLED: WRITE 8->12MB,
//    attn 68.5->74 — do not re-add).
//  - stage MUST be jj<4 (R7/R8 NaN: jj<2 left half the tile unstaged).
__global__ __launch_bounds__(256, 4) void attn_kernel(
    const unsigned short* __restrict__ Qb, const unsigned short* __restrict__ Kb,
    const unsigned short* __restrict__ Vt, const unsigned long long* __restrict__ Mb,
    unsigned short* __restrict__ Ob)
{
    const int flat = blockIdx.x + 32 * blockIdx.y + 256 * blockIdx.z;
    const int hb = flat & 7;             // head -> XCD (dispatch round-robin)
    const int qt = (flat >> 3) & 31;     // 0..31, 64 q per block
    const int b  = flat >> 8;
    const int q0 = qt * 64;
    const int tid = threadIdx.x, lane = tid & 63, w = tid >> 6;
    const int l31 = lane & 31, hf = lane >> 5;
    const int half = w >> 1;             // token half: 0 -> tok 0..1023, 1 -> 1024..2047
    const int qgrp = w & 1;              // q-group within block

    // 32 KB shared: per-half single-buffered K and V tiles (64 tok x 64 d).
    // Reused as the f32 merge buffer at the epilogue.
    __shared__ unsigned short SM[16384];
    unsigned short* KsH = SM + half * 4096;
    unsigned short* VsH = SM + 8192 + half * 4096;

    const int qg = q0 + qgrp * 32 + l31;
    const size_t qoff = ((size_t)b * Sc + qg) * HDc + hb * Dc;

    // Q B-fragments: slice s4 holds d = 16*s4 + 8*hf + (0..7)
    bf16x8 qf[4];
#pragma unroll
    for (int s4 = 0; s4 < 4; s4++)
        qf[s4] = *(const bf16x8*)(Qb + qoff + s4 * 16 + hf * 8);

    const unsigned long long* mr = Mb + ((size_t)b * Sc + qg) * (Sc / 64);
    const size_t kbase = ((size_t)b * Sc) * HDc + hb * Dc;
    const size_t vbase = ((size_t)(b * Hc + hb)) * Dc * Sc;

    f32x16 o[2];
#pragma unroll
    for (int i = 0; i < 16; i++) { o[0][i] = 0.f; o[1][i] = 0.f; }
    float os[4] = {0.f, 0.f, 0.f, 0.f};
    const f16x2 one2 = {(_Float16)1.0f, (_Float16)1.0f};

    // stage tile t into this half's buffers; the half's 2 waves cooperate:
    // jj<4 x 8 rows x 2 waves = all 64 rows of K and V tiles.
    auto stage = [&](int t) {
#pragma unroll
        for (int jj = 0; jj < 4; jj++) {
            int rb = qgrp * 32 + jj * 8;
            int row = rb + (lane >> 3);
            int dg = (lane & 7) ^ (row & 7);
            gload_lds(Kb + kbase + (size_t)(t * 64 + row) * HDc + dg * 8, &KsH[rb * 64]);
            gload_lds(Vt + vbase + (size_t)row * Sc + t * 64 + dg * 8, &VsH[rb * 64]);
        }
    };

    for (int i = 0; i < 16; i++) {
        const int t = half * 16 + i;     // absolute 64-token tile id
        unsigned long long mw = mr[t];
        stage(t);
        __syncthreads();                 // drains async loads -> tiles ready

        // S^T per 32-token group: lane holds tok = 32a + 8g + 4hf + r, q = l31
        u32 P16[2][8];
#pragma unroll
        for (int a = 0; a < 2; a++) {
            f32x16 s;
#pragma unroll
            for (int i2 = 0; i2 < 16; i2++) s[i2] = 0.f;
            const int tk = a * 32 + l31;
            __builtin_amdgcn_s_setprio(1);
#pragma unroll
            for (int s4 = 0; s4 < 4; s4++) {
                bf16x8 kf = *(const bf16x8*)&KsH[tk * 64 + (((2 * s4 + hf) ^ (tk & 7)) * 8)];
                s = __builtin_amdgcn_mfma_f32_32x32x16_bf16(kf, qf[s4], s, 0, 0, 0);
            }
            __builtin_amdgcn_s_setprio(0);
            u32 mwa = (a == 0) ? (u32)mw : (u32)(mw >> 32);
            int mq = (int)(mwa >> (4 * hf));
#pragma unroll
            for (int g = 0; g < 4; g++) {
                float p[4];
#pragma unroll
                for (int r = 0; r < 4; r++) {
                    const int pos = 8 * g + r;                       // mask bit
                    int keep = __builtin_amdgcn_sbfe(mq, pos, 1);    // -1 if unmasked
                    float e = __builtin_amdgcn_exp2f(s[4 * g + r]);  // bare v_exp_f32
                    p[r] = __int_as_float(__float_as_int(e) & keep);
                }
                u32 u0 = pkh2(p[0], p[1]);
                u32 u1 = pkh2(p[2], p[3]);
                P16[a][2 * g + 0] = u0;
                P16[a][2 * g + 1] = u1;
                union { u32 u; f16x2 h; } d0, d1;
                d0.u = u0; d1.u = u1;
                os[g] = __builtin_amdgcn_fdot2(d0.h, one2, os[g], false);
                os[g] = __builtin_amdgcn_fdot2(d1.h, one2, os[g], false);
            }
        }

        // Batched lane-half exchange (8 shfls issued together)
        u32 pw[4][4];
#pragma unroll
        for (int s4 = 0; s4 < 4; s4++) {
            const int a = s4 >> 1, base = 4 * (s4 & 1);
#pragma unroll
            for (int pp = 0; pp < 2; pp++) {
                u32 A0 = P16[a][base + pp];        // words for ho=0 tokens
                u32 B1 = P16[a][base + 2 + pp];    // words for ho=1 tokens
                u32 sent = hf ? A0 : B1;
                u32 got = (u32)__shfl_xor((int)sent, 32, 64);
                pw[s4][pp]     = hf ? got : A0;    // j=0..3  (from half 0)
                pw[s4][2 + pp] = hf ? B1  : got;   // j=4..7  (from half 1)
            }
        }
        __builtin_amdgcn_s_setprio(1);
#pragma unroll
        for (int s4 = 0; s4 < 4; s4++) {
            union { u32 u[4]; f16x8 v; } pf;
            pf.u[0] = pw[s4][0]; pf.u[1] = pw[s4][1];
            pf.u[2] = pw[s4][2]; pf.u[3] = pw[s4][3];
#pragma unroll
            for (int dt = 0; dt < 2; dt++) {
                const int d = dt * 32 + l31;
                f16x8 vf = *(const f16x8*)&VsH[d * 64 + (((2 * s4 + hf) ^ (d & 7)) * 8)];
                o[dt] = __builtin_amdgcn_mfma_f32_32x32x16_f16(vf, pf.v, o[dt], 0, 0, 0);
            }
        }
        __builtin_amdgcn_s_setprio(0);
        __syncthreads();                 // tiles reusable for next iteration
    }

    // each lane summed only its hf-half of its token range; partner lane
    // (lane^32) has the rest of this HALF's tokens
    float osum = os[0] + os[1] + os[2] + os[3];
    osum += __shfl_xor(osum, 32, 64);

    // ---- cross-half merge via LDS (exact: partials add, then normalize) ----
    float* mbuf = (float*)SM;            // [qgrp][lane][34] floats = 17.4 KB
    if (half == 1) {
        float* mp = mbuf + (qgrp * 64 + lane) * 34;
#pragma unroll
        for (int dt = 0; dt < 2; dt++)
#pragma unroll
            for (int i = 0; i < 16; i++) mp[dt * 16 + i] = o[dt][i];
        mp[32] = osum;
    }
    __syncthreads();
    if (half == 0) {
        const float* mp = mbuf + (qgrp * 64 + lane) * 34;
#pragma unroll
        for (int dt = 0; dt < 2; dt++)
#pragma unroll
            for (int i = 0; i < 16; i++) o[dt][i] += mp[dt * 16 + i];
        const float inv = 1.0f / (osum + mp[32]);
#pragma unroll
        for (int dt = 0; dt < 2; dt++)
#pragma unroll
            for (int g = 0; g < 4; g++) {
                const int d = dt * 32 + 8 * g + 4 * hf;
                uint2 pk;
                pk.x = pkbf2(o[dt][4 * g + 0] * inv, o[dt][4 * g + 1] * inv);
                pk.y = pkbf2(o[dt][4 * g + 2] * inv, o[dt][4 * g + 3] * inv);
                *(uint2*)(Ob + qoff + d) = pk;
            }
    }
}

// ---------------------------------------------------------------------------
// Kernel 4: output projection, 64x128 tiles. grid (4 n-blocks, 128 m-blocks).
__global__ __launch_bounds__(256) void out_gemm(
    const unsigned short* __restrict__ Ab, const unsigned short* __restrict__ Bt,
    const float* __restrict__ bias, float* __restrict__ Out)
{
    const int n0 = blockIdx.x * 128;
    const int m0 = blockIdx.y * 64;
    const int tid = threadIdx.x, lane = tid & 63, w = tid >> 6;
    const int c = lane & 15, quad = lane >> 4;
    const int wm = w & 1, wn = w >> 1;

    __shared__ unsigned short As[64 * 64];
    __shared__ unsigned short Bs[128 * 64];

    f32x4 acc[2][4];
#pragma unroll
    for (int i = 0; i < 2; i++)
#pragma unroll
        for (int j = 0; j < 4; j++) acc[i][j] = (f32x4){0.f, 0.f, 0.f, 0.f};

    for (int k0 = 0; k0 < HDc; k0 += 64) {
        __syncthreads();
#pragma unroll
        for (int jj = 0; jj < 4; jj++) {
            int rb = w * 32 + jj * 8;
            int row = rb + (lane >> 3);
            int dg = (lane & 7) ^ (row & 7);
            gload_lds(Bt + (size_t)(n0 + row) * Ec + k0 + dg * 8, &Bs[rb * 64]);
        }
#pragma unroll
        for (int jj = 0; jj < 2; jj++) {
            int rb = w * 16 + jj * 8;
            int row = rb + (lane >> 3);
            int dg = (lane & 7) ^ (row & 7);
            gload_lds(Ab + (size_t)(m0 + row) * HDc + k0 + dg * 8, &As[rb * 64]);
        }
        __syncthreads();
#pragma unroll
        for (int ks = 0; ks < 2; ks++) {
            int kg = ks * 4 + quad;
            bf16x8 af[2], bfr[4];
#pragma unroll
            for (int mt = 0; mt < 2; mt++) {
                int row = wm * 32 + mt * 16 + c;
                af[mt] = *(const bf16x8*)&As[row * 64 + ((kg ^ (row & 7)) * 8)];
            }
#pragma unroll
            for (int nt = 0; nt < 4; nt++) {
                int row = wn * 64 + nt * 16 + c;
                bfr[nt] = *(const bf16x8*)&Bs[row * 64 + ((kg ^ (row & 7)) * 8)];
            }
#pragma unroll
            for (int mt = 0; mt < 2; mt++)
#pragma unroll
                for (int nt = 0; nt < 4; nt++)
                    acc[mt][nt] = __builtin_amdgcn_mfma_f32_16x16x32_bf16(af[mt], bfr[nt], acc[mt][nt], 0, 0, 0);
        }
    }
#pragma unroll
    for (int mt = 0; mt < 2; mt++)
#pragma unroll
        for (int r = 0; r < 4; r++) {
            int gm = m0 + wm * 32 + mt * 16 + quad * 4 + r;
#pragma unroll
            for (int nt = 0; nt < 4; nt++) {
                int gn = n0 + wn * 64 + nt * 16 + c;
                Out[(size_t)gm * Ec + gn] = acc[mt][nt][r] + bias[gn];
            }
        }
}

// ---------------------------------------------------------------------------
extern "C" void kernel_launch(void* const* d_in, const int* in_sizes, int n_in,
                              void* d_out, int out_size, void* d_ws, size_t ws_size,
                              hipStream_t stream)
{
    const float* xq = (const float*)d_in[0];
    const float* xk = (const float*)d_in[1];
    const float* xv = (const float*)d_in[2];
    const int* mask = (const int*)d_in[3];
    const float* wq = (const float*)d_in[4];
    const float* bq = (const float*)d_in[5];
    const float* wk = (const float*)d_in[6];
    const float* bk = (const float*)d_in[7];
    const float* wv = (const float*)d_in[8];
    const float* bv = (const float*)d_in[9];
    const float* wo = (const float*)d_in[10];
    const float* bo = (const float*)d_in[11];
    float* out = (float*)d_out;

    char* ws = (char*)d_ws;
    const size_t MB = 1024 * 1024;
    unsigned short* qb = (unsigned short*)(ws + 0 * MB);    // 8 MB
    unsigned short* kb = (unsigned short*)(ws + 8 * MB);    // 8 MB
    unsigned short* vt = (unsigned short*)(ws + 16 * MB);   // 8 MB
    unsigned short* xb = (unsigned short*)(ws + 24 * MB);   // 24 MB (dead after proj)
    unsigned short* ab = (unsigned short*)(ws + 24 * MB);   // 8 MB (reuses xb space)
    unsigned long long* mb = (unsigned long long*)(ws + 48 * MB); // 2 MB
    unsigned short* wt = (unsigned short*)(ws + 50 * MB);   // 2 MB

    hipLaunchKernelGGL(prep, dim3(8448), dim3(256), 0, stream,
                       mask, mb, wq, wk, wv, wo, wt, xq, xk, xv, xb);

    hipLaunchKernelGGL(proj_gemm, dim3(4, 64, 3), dim3(256), 0, stream,
                       xb, wt, bq, bk, bv, qb, kb, vt);

    hipLaunchKernelGGL(attn_kernel, dim3(32, 8, 4), dim3(256), 0, stream,
                       qb, kb, vt, mb, ab);

    hipLaunchKernelGGL(out_gemm, dim3(4, 128), dim3(256), 0, stream,
                       ab, wt + 3 * (size_t)Ec * HDc, bo, out);
}